// Round 3
// baseline (298.345 us; speedup 1.0000x reference)
//
#include <hip/hip_runtime.h>
#include <stdint.h>

// MinGRU fused pipeline (round 2 resubmit — round 2 bench hit GPUAcquisitionTimeout):
//   1) ln_kernel:   x [BT,H] f32 -> normed bf16; one WAVE per row (no LDS/barriers)
//   2) pack_kernel: Wg,Wc f32 -> wpack [2048,1024] bf16 (B^T layout, K-contig)
//   3) gemm_kernel: 128x128 tile, BK=32, DOUBLE-BUFFERED prefetch (T3 minimum
//      2-phase: stage next before compute, ONE barrier per K-step)
//   4) scans: CHK=128 chunks, VEC=4 channels/thread, uint2/float4 loads

#define B_    4
#define T_    4096
#define H_    1024
#define BT_   (B_*T_)       // 16384
#define EPSV  1e-5f
#define CHK   128           // chunks over T
#define CL    (T_/CHK)      // 32 steps per chunk

typedef float  f32x4  __attribute__((ext_vector_type(4)));
typedef __bf16 bf16x8 __attribute__((ext_vector_type(8)));
typedef unsigned short u16;

__device__ __forceinline__ u16 f2bf(float f) {            // RNE f32->bf16
  uint32_t u = __builtin_bit_cast(uint32_t, f);
  u += 0x7fffu + ((u >> 16) & 1u);
  return (u16)(u >> 16);
}
__device__ __forceinline__ float bf2f(uint32_t u) {
  uint32_t v = (u & 0xffffu) << 16;
  return __builtin_bit_cast(float, v);
}
__device__ __forceinline__ void bf4(uint2 p, float* f) {  // 4 bf16 -> 4 f32
  f[0] = bf2f(p.x); f[1] = bf2f(p.x >> 16);
  f[2] = bf2f(p.y); f[3] = bf2f(p.y >> 16);
}

// ---------------- LayerNorm: one WAVE per row, shfl-only reduce ----------------
__global__ __launch_bounds__(256) void ln_kernel(
    const float* __restrict__ x, const float* __restrict__ gamma,
    const float* __restrict__ beta, u16* __restrict__ normed) {
  const int wid  = threadIdx.x >> 6, lane = threadIdx.x & 63;
  const int row  = blockIdx.x * 4 + wid;
  const float4* xr = reinterpret_cast<const float4*>(x + (size_t)row * H_);
  float4 v[4];
  float s = 0.0f, q = 0.0f;
  #pragma unroll
  for (int seg = 0; seg < 4; ++seg) {
    v[seg] = xr[seg * 64 + lane];
    s += v[seg].x + v[seg].y + v[seg].z + v[seg].w;
    q += v[seg].x*v[seg].x + v[seg].y*v[seg].y + v[seg].z*v[seg].z + v[seg].w*v[seg].w;
  }
  #pragma unroll
  for (int off = 1; off < 64; off <<= 1) {
    s += __shfl_xor(s, off);
    q += __shfl_xor(q, off);
  }
  const float mean = s * (1.0f / H_);
  const float var  = q * (1.0f / H_) - mean * mean;
  const float rstd = rsqrtf(var + EPSV);
  const float4* g4 = reinterpret_cast<const float4*>(gamma);
  const float4* b4 = reinterpret_cast<const float4*>(beta);
  uint2* o2 = reinterpret_cast<uint2*>(normed + (size_t)row * H_);
  #pragma unroll
  for (int seg = 0; seg < 4; ++seg) {
    const float4 g = g4[seg * 64 + lane];
    const float4 b = b4[seg * 64 + lane];
    uint2 o;
    o.x = (uint32_t)f2bf((v[seg].x - mean) * rstd * g.x + b.x)
        | ((uint32_t)f2bf((v[seg].y - mean) * rstd * g.y + b.y) << 16);
    o.y = (uint32_t)f2bf((v[seg].z - mean) * rstd * g.z + b.z)
        | ((uint32_t)f2bf((v[seg].w - mean) * rstd * g.w + b.w) << 16);
    o2[seg * 64 + lane] = o;
  }
}

// ---------------- weight pack: [Wg;Wc] f32 -> bf16 [2048][1024] ----------------
__global__ __launch_bounds__(256) void pack_kernel(
    const float* __restrict__ Wg, const float* __restrict__ Wc,
    u16* __restrict__ wpack) {
  const int idx4 = (blockIdx.x * 256 + threadIdx.x) * 4;
  const int n = idx4 >> 10;
  const int k = idx4 & 1023;
  const float* src = (n < 1024) ? (Wg + (size_t)n * 1024 + k)
                                : (Wc + (size_t)(n - 1024) * 1024 + k);
  const float4 v = *reinterpret_cast<const float4*>(src);
  uint2 o;
  o.x = (uint32_t)f2bf(v.x) | ((uint32_t)f2bf(v.y) << 16);
  o.y = (uint32_t)f2bf(v.z) | ((uint32_t)f2bf(v.w) << 16);
  *reinterpret_cast<uint2*>(wpack + idx4) = o;
}

// ---------------- GEMM 128x128 tile, BK=32, 4 waves, double-buffered ----------
// out[bt][n] = sum_h normed[bt][h]*wpack[n][h];  n<1024 -> z=sigmoid(+bg) ; else c=+bc
__global__ __launch_bounds__(256) void gemm_kernel(
    const u16* __restrict__ A, const u16* __restrict__ Bw,
    const float* __restrict__ bg, const float* __restrict__ bc,
    u16* __restrict__ zbuf, u16* __restrict__ cbuf) {
  __shared__ u16 As[2][128 * 32];
  __shared__ u16 Bs[2][128 * 32];
  const int bid = blockIdx.x;
  const int nb  = (bid & 7) * 256 + (bid >> 3);   // XCD-aware swizzle (2048 % 8 == 0)
  const int mt  = nb >> 4, nt = nb & 15;
  const int tid = threadIdx.x;
  const int wid = tid >> 6, lane = tid & 63;
  const int wr = wid >> 1, wcq = wid & 1;

  f32x4 acc[4][4] = {};

  // staging: chunk c (16B = 8 bf16): row = c>>2, k8 = c&3; LDS linear at c*8 elems
  const int c0 = tid, c1 = tid + 256;
  const u16* a0 = A  + (size_t)(mt * 128 + (c0 >> 2)) * 1024 + (c0 & 3) * 8;
  const u16* a1 = A  + (size_t)(mt * 128 + (c1 >> 2)) * 1024 + (c1 & 3) * 8;
  const u16* b0 = Bw + (size_t)(nt * 128 + (c0 >> 2)) * 1024 + (c0 & 3) * 8;
  const u16* b1 = Bw + (size_t)(nt * 128 + (c1 >> 2)) * 1024 + (c1 & 3) * 8;

  const int frow = lane & 15;
  const int kb   = (lane >> 4) * 8;

  auto stage = [&](int buf, int ks) {
    const int kk = ks * 32;
    __builtin_amdgcn_global_load_lds(
        (const __attribute__((address_space(1))) void*)(a0 + kk),
        (__attribute__((address_space(3))) void*)&As[buf][c0 * 8], 16, 0, 0);
    __builtin_amdgcn_global_load_lds(
        (const __attribute__((address_space(1))) void*)(a1 + kk),
        (__attribute__((address_space(3))) void*)&As[buf][c1 * 8], 16, 0, 0);
    __builtin_amdgcn_global_load_lds(
        (const __attribute__((address_space(1))) void*)(b0 + kk),
        (__attribute__((address_space(3))) void*)&Bs[buf][c0 * 8], 16, 0, 0);
    __builtin_amdgcn_global_load_lds(
        (const __attribute__((address_space(1))) void*)(b1 + kk),
        (__attribute__((address_space(3))) void*)&Bs[buf][c1 * 8], 16, 0, 0);
  };
  auto compute = [&](int buf) {
    bf16x8 af[4], bfr[4];
    #pragma unroll
    for (int m = 0; m < 4; ++m)
      af[m] = *reinterpret_cast<const bf16x8*>(&As[buf][(wr * 64 + m * 16 + frow) * 32 + kb]);
    #pragma unroll
    for (int n = 0; n < 4; ++n)
      bfr[n] = *reinterpret_cast<const bf16x8*>(&Bs[buf][(wcq * 64 + n * 16 + frow) * 32 + kb]);
    #pragma unroll
    for (int m = 0; m < 4; ++m)
      #pragma unroll
      for (int n = 0; n < 4; ++n)
        acc[m][n] = __builtin_amdgcn_mfma_f32_16x16x32_bf16(af[m], bfr[n], acc[m][n], 0, 0, 0);
  };

  stage(0, 0);
  __syncthreads();                 // drains vmcnt(0): buf0 ready
  int cur = 0;
  for (int ks = 0; ks < 31; ++ks) {
    stage(cur ^ 1, ks + 1);        // loads fly while we compute cur
    compute(cur);
    __syncthreads();               // one barrier/iter: next buf ready + reads of cur done
    cur ^= 1;
  }
  compute(cur);                    // last K-step, no prefetch

  // epilogue: C/D layout col = lane&15, row = (lane>>4)*4 + r  [m89]
  const int r0  = (lane >> 4) * 4;
  const int col16 = lane & 15;
  const bool isz = (nt < 8);   // block-uniform: whole tile is z-half or c-half
  #pragma unroll
  for (int m = 0; m < 4; ++m) {
    #pragma unroll
    for (int n = 0; n < 4; ++n) {
      const int col = nt * 128 + wcq * 64 + n * 16 + col16;
      #pragma unroll
      for (int r = 0; r < 4; ++r) {
        const int row = mt * 128 + wr * 64 + m * 16 + r0 + r;   // bt index
        float v = acc[m][n][r];
        if (isz) {
          v += bg[col];
          v = 1.0f / (1.0f + __expf(-v));
          zbuf[(size_t)row * 1024 + col] = f2bf(v);
        } else {
          const int cc = col - 1024;
          v += bc[cc];
          cbuf[(size_t)row * 1024 + cc] = f2bf(v);
        }
      }
    }
  }
}

// ---------------- scan phase 1: per-chunk (prod a, partial h), VEC=4 ----------
__global__ __launch_bounds__(256) void scan1_kernel(
    const u16* __restrict__ zbuf, const u16* __restrict__ cbuf,
    float* __restrict__ Achk, float* __restrict__ Uchk) {
  const int bid   = blockIdx.x;            // [0, B_*CHK)
  const int chunk = bid & (CHK - 1);
  const int b     = bid >> 7;              // CHK=128
  const int o4    = threadIdx.x * 4;
  const size_t base = ((size_t)(b * T_ + chunk * CL)) * H_ + o4;
  float A[4] = {1.f, 1.f, 1.f, 1.f};
  float u[4] = {0.f, 0.f, 0.f, 0.f};
  #pragma unroll 4
  for (int t = 0; t < CL; ++t) {
    const size_t idx = base + (size_t)t * H_;
    const uint2 zp = *reinterpret_cast<const uint2*>(&zbuf[idx]);
    const uint2 cp = *reinterpret_cast<const uint2*>(&cbuf[idx]);
    float z[4], c[4];
    bf4(zp, z); bf4(cp, c);
    #pragma unroll
    for (int j = 0; j < 4; ++j) {
      const float a = 1.0f - z[j];
      A[j] *= a;
      u[j] = a * u[j] + z[j] * c[j];
    }
  }
  const int idx = (b * CHK + chunk) * H_ + o4;
  *reinterpret_cast<float4*>(&Achk[idx]) = make_float4(A[0], A[1], A[2], A[3]);
  *reinterpret_cast<float4*>(&Uchk[idx]) = make_float4(u[0], u[1], u[2], u[3]);
}

// ---------------- scan phase 2: cross-chunk prefix (tiny) ----------------
__global__ __launch_bounds__(256) void scan2_kernel(
    const float* __restrict__ Achk, const float* __restrict__ Uchk,
    float* __restrict__ Hin) {
  const int g = blockIdx.x * 256 + threadIdx.x;   // [0, B_*H_)
  const int b = g >> 10;
  const int o = g & 1023;
  float h = 0.0f;
  #pragma unroll 8
  for (int j = 0; j < CHK; ++j) {
    const int idx = (b * CHK + j) * H_ + o;
    Hin[idx] = h;                       // h BEFORE chunk j
    h = Achk[idx] * h + Uchk[idx];
  }
}

// ---------------- scan phase 3: replay with h_in, add residual, VEC=4 ---------
__global__ __launch_bounds__(256) void scan3_kernel(
    const u16* __restrict__ zbuf, const u16* __restrict__ cbuf,
    const float* __restrict__ Hin, const float* __restrict__ x,
    float* __restrict__ out) {
  const int bid   = blockIdx.x;
  const int chunk = bid & (CHK - 1);
  const int b     = bid >> 7;
  const int o4    = threadIdx.x * 4;
  const float4 hv = *reinterpret_cast<const float4*>(&Hin[(b * CHK + chunk) * H_ + o4]);
  float h[4] = {hv.x, hv.y, hv.z, hv.w};
  const size_t base = ((size_t)(b * T_ + chunk * CL)) * H_ + o4;
  #pragma unroll 4
  for (int t = 0; t < CL; ++t) {
    const size_t idx = base + (size_t)t * H_;
    const uint2 zp = *reinterpret_cast<const uint2*>(&zbuf[idx]);
    const uint2 cp = *reinterpret_cast<const uint2*>(&cbuf[idx]);
    const float4 xv = *reinterpret_cast<const float4*>(&x[idx]);
    float z[4], c[4];
    bf4(zp, z); bf4(cp, c);
    #pragma unroll
    for (int j = 0; j < 4; ++j)
      h[j] = (1.0f - z[j]) * h[j] + z[j] * c[j];
    *reinterpret_cast<float4*>(&out[idx]) =
        make_float4(h[0] + xv.x, h[1] + xv.y, h[2] + xv.z, h[3] + xv.w);
  }
}

extern "C" void kernel_launch(void* const* d_in, const int* in_sizes, int n_in,
                              void* d_out, int out_size, void* d_ws, size_t ws_size,
                              hipStream_t stream) {
  const float* x     = (const float*)d_in[0];
  const float* gamma = (const float*)d_in[1];
  const float* beta  = (const float*)d_in[2];
  const float* Wg    = (const float*)d_in[3];
  const float* bg    = (const float*)d_in[4];
  const float* Wc    = (const float*)d_in[5];
  const float* bc    = (const float*)d_in[6];
  float* out = (float*)d_out;

  char* ws = (char*)d_ws;
  u16*   normed = (u16*)(ws);                         // 32 MB (dead after gemm)
  u16*   wpack  = (u16*)(ws + 33554432ull);           //  4 MB
  u16*   zbuf   = (u16*)(ws + 37748736ull);           // 32 MB
  u16*   cbuf   = (u16*)(ws + 71303168ull);           // 32 MB
  // scan temporaries overlay the dead `normed` region (2 MB each)
  float* Achk   = (float*)(ws);
  float* Uchk   = (float*)(ws + 2097152ull);
  float* Hin    = (float*)(ws + 4194304ull);

  ln_kernel  <<<BT_/4, 256, 0, stream>>>(x, gamma, beta, normed);
  pack_kernel<<<2048,  256, 0, stream>>>(Wg, Wc, wpack);
  gemm_kernel<<<2048,  256, 0, stream>>>(normed, wpack, bg, bc, zbuf, cbuf);
  scan1_kernel<<<B_*CHK, 256, 0, stream>>>(zbuf, cbuf, Achk, Uchk);
  scan2_kernel<<<16,     256, 0, stream>>>(Achk, Uchk, Hin);
  scan3_kernel<<<B_*CHK, 256, 0, stream>>>(zbuf, cbuf, Hin, x, out);
}